// Round 1
// baseline (1658.895 us; speedup 1.0000x reference)
//
#include <hip/hip_runtime.h>
#include <stdint.h>

#define DIM 2048
#define HID 5632
#define SEQ 8192
#define NW3 (3*HID)            // 16896
#define CONV 4
#define CHUNK 64

typedef __attribute__((ext_vector_type(8))) __bf16 bf16x8;
typedef __attribute__((ext_vector_type(4))) float f32x4;

__device__ __forceinline__ uint16_t f2bf(float f) {
  union { float f; uint32_t u; } v; v.f = f;
  return (uint16_t)((v.u + 0x7FFFu + ((v.u >> 16) & 1u)) >> 16);
}
__device__ __forceinline__ float bf2f(uint16_t h) {
  union { uint32_t u; float f; } v; v.u = ((uint32_t)h) << 16;
  return v.f;
}

// ---------------- fp32 -> bf16 conversion (vectorized x4) ----------------
__global__ void cvt4_kernel(const float* __restrict__ src, uint16_t* __restrict__ dst, int n4) {
  int i = blockIdx.x * blockDim.x + threadIdx.x;
  if (i >= n4) return;
  float4 v = ((const float4*)src)[i];
  ushort4 o;
  o.x = f2bf(v.x); o.y = f2bf(v.y); o.z = f2bf(v.z); o.w = f2bf(v.w);
  ((ushort4*)dst)[i] = o;
}

__device__ __forceinline__ void load_lds16(const void* g, void* l) {
  __builtin_amdgcn_global_load_lds(
      (__attribute__((address_space(1))) void*)g,
      (__attribute__((address_space(3))) void*)l, 16, 0, 0);
}

// ---------------- 256x256 8-phase bf16 GEMM: C = A(M,K;LDA) * B(N,K;LDB)^T ----
// 512 threads = 8 waves (2M x 4N), BK=64, LDS 128 KiB double-buffered.
// LDS layout per (buf, khalf): [256][32] bf16 with XOR swizzle
//   phys_kslice = kslice ^ ((row>>1)&3)   (bank-conflict-free ds_read_b128)
// applied via inverse-swizzled GLOBAL source (global_load_lds dest stays linear)
// and swizzled ds_read address.
// Pipeline per K-tile t (buffer c=t&1):
//   P1: read kh0 frags A0-3,B0-3 | stage A.kh1(t+1)->c^1 | bar | lgkm0 | 16 MFMA | bar
//   P2: read kh0 frags A4-7      | stage B.kh1(t+1)->c^1 | bar | lgkm0 | 16 MFMA | vmcnt(8) | bar
//   P3: read kh1 frags A0-3,B0-3 | stage A.kh0(t+2)->c   | bar | lgkm0 | 16 MFMA | bar
//   P4: read kh1 frags A4-7      | stage B.kh0(t+2)->c   | bar | lgkm0 | 16 MFMA | vmcnt(8) | bar
// vmcnt(8) is exact in steady state (16 loads in flight, oldest 8 = data needed
// next); tail iterations issue clamped dummy stages to keep counts uniform.
// OUT_MODE: 0 = fp32 store, 1 = bf16 store, 2 = fp32 atomicAdd (split-K via blockIdx.y)
template<int LDA, int LDB, int LDC, int KLEN, int OUT_MODE>
__global__ __launch_bounds__(512, 2)
void gemm256(const uint16_t* __restrict__ A, const uint16_t* __restrict__ B,
             void* __restrict__ C, int nbx)
{
  __shared__ alignas(16) uint16_t As[2][2][256][32];
  __shared__ alignas(16) uint16_t Bs[2][2][256][32];
  constexpr int NT = KLEN / 64;

  const int tid  = threadIdx.x;
  const int wave = tid >> 6;
  const int lane = tid & 63;

  // bijective XCD-aware swizzle (m204)
  const int nwg = (int)gridDim.x;
  const int bid = (int)blockIdx.x;
  const int qq  = nwg >> 3, rr = nwg & 7;
  const int xcd = bid & 7, loc = bid >> 3;
  const int swz = (xcd < rr ? xcd*(qq+1) : rr*(qq+1) + (xcd-rr)*qq) + loc;
  const int row0 = (swz % nbx) * 256;
  const int col0 = (swz / nbx) * 256;

  const uint16_t* Ab = A + (size_t)blockIdx.y * KLEN;   // split-K slice
  const uint16_t* Bb = B + (size_t)blockIdx.y * KLEN;

  const int wr = wave >> 2;          // 0..1 -> rows wr*128..
  const int wc = wave & 3;           // 0..3 -> cols wc*64..
  const int rm = lane & 15;
  const int kq8 = ((lane >> 4) ^ ((rm >> 1) & 3)) * 8;  // swizzled k-slice (elems)
  const int ri = wr*128 + rm;
  const int ci = wc*64 + rm;

  // staging: per thread 2 loads per 16KB half; granule g = j*512+tid holds
  // logical row g>>2, k-slice (g&3)^((row>>1)&3)  (inverse swizzle at source)
  size_t offA0, offA1, offB0, offB1;
  {
    const int g0 = tid,       r0_ = g0 >> 2, k0_ = (g0 & 3) ^ ((r0_ >> 1) & 3);
    const int g1 = 512 + tid, r1_ = g1 >> 2, k1_ = (g1 & 3) ^ ((r1_ >> 1) & 3);
    offA0 = (size_t)(row0 + r0_)*LDA + k0_*8;
    offA1 = (size_t)(row0 + r1_)*LDA + k1_*8;
    offB0 = (size_t)(col0 + r0_)*LDB + k0_*8;
    offB1 = (size_t)(col0 + r1_)*LDB + k1_*8;
  }

#define STAGE_A(kt,h,buf) do {                                              \
    const size_t ko_ = (size_t)(kt)*64 + (size_t)(h)*32;                    \
    load_lds16(Ab + offA0 + ko_, &As[(buf)][(h)][wave*16][0]);              \
    load_lds16(Ab + offA1 + ko_, &As[(buf)][(h)][128 + wave*16][0]);        \
  } while (0)
#define STAGE_B(kt,h,buf) do {                                              \
    const size_t ko_ = (size_t)(kt)*64 + (size_t)(h)*32;                    \
    load_lds16(Bb + offB0 + ko_, &Bs[(buf)][(h)][wave*16][0]);              \
    load_lds16(Bb + offB1 + ko_, &Bs[(buf)][(h)][128 + wave*16][0]);        \
  } while (0)

  f32x4 acc[8][4];
  #pragma unroll
  for (int i = 0; i < 8; ++i)
    #pragma unroll
    for (int j = 0; j < 4; ++j) acc[i][j] = (f32x4){0.f,0.f,0.f,0.f};

  // prologue: tile0 kh0+kh1 -> buf0, tile1 kh0 -> buf1 (12 loads/thread)
  STAGE_A(0,0,0); STAGE_B(0,0,0);
  STAGE_A(0,1,0); STAGE_B(0,1,0);
  {
    const int t1 = (NT > 1) ? 1 : 0;
    STAGE_A(t1,0,1); STAGE_B(t1,0,1);
  }
  asm volatile("s_waitcnt vmcnt(8)" ::: "memory");
  __builtin_amdgcn_s_barrier();

  #pragma unroll 1
  for (int t = 0; t < NT; ++t) {
    const int c   = t & 1;
    const int tn1 = (t+1 < NT) ? t+1 : NT-1;   // clamped (dummy) at tail
    const int tn2 = (t+2 < NT) ? t+2 : NT-1;
    bf16x8 af[4], bfr[4];

    // ---- phase 1: kh0, M-frags 0..3 ----
    #pragma unroll
    for (int i = 0; i < 4; ++i) af[i]  = *(const bf16x8*)&As[c][0][ri + i*16][kq8];
    #pragma unroll
    for (int j = 0; j < 4; ++j) bfr[j] = *(const bf16x8*)&Bs[c][0][ci + j*16][kq8];
    STAGE_A(tn1, 1, c^1);
    __builtin_amdgcn_s_barrier();
    asm volatile("s_waitcnt lgkmcnt(0)" ::: "memory");
    __builtin_amdgcn_sched_barrier(0);
    __builtin_amdgcn_s_setprio(1);
    #pragma unroll
    for (int i = 0; i < 4; ++i)
      #pragma unroll
      for (int j = 0; j < 4; ++j)
        acc[i][j] = __builtin_amdgcn_mfma_f32_16x16x32_bf16(af[i], bfr[j], acc[i][j], 0, 0, 0);
    __builtin_amdgcn_s_setprio(0);
    __builtin_amdgcn_s_barrier();

    // ---- phase 2: kh0, M-frags 4..7 ----
    #pragma unroll
    for (int i = 0; i < 4; ++i) af[i] = *(const bf16x8*)&As[c][0][ri + (i+4)*16][kq8];
    STAGE_B(tn1, 1, c^1);
    __builtin_amdgcn_s_barrier();
    asm volatile("s_waitcnt lgkmcnt(0)" ::: "memory");
    __builtin_amdgcn_sched_barrier(0);
    __builtin_amdgcn_s_setprio(1);
    #pragma unroll
    for (int i = 0; i < 4; ++i)
      #pragma unroll
      for (int j = 0; j < 4; ++j)
        acc[i+4][j] = __builtin_amdgcn_mfma_f32_16x16x32_bf16(af[i], bfr[j], acc[i+4][j], 0, 0, 0);
    __builtin_amdgcn_s_setprio(0);
    asm volatile("s_waitcnt vmcnt(8)" ::: "memory");   // kh1 of tile t landed
    __builtin_amdgcn_s_barrier();

    // ---- phase 3: kh1, M-frags 0..3 ----
    #pragma unroll
    for (int i = 0; i < 4; ++i) af[i]  = *(const bf16x8*)&As[c][1][ri + i*16][kq8];
    #pragma unroll
    for (int j = 0; j < 4; ++j) bfr[j] = *(const bf16x8*)&Bs[c][1][ci + j*16][kq8];
    STAGE_A(tn2, 0, c);
    __builtin_amdgcn_s_barrier();
    asm volatile("s_waitcnt lgkmcnt(0)" ::: "memory");
    __builtin_amdgcn_sched_barrier(0);
    __builtin_amdgcn_s_setprio(1);
    #pragma unroll
    for (int i = 0; i < 4; ++i)
      #pragma unroll
      for (int j = 0; j < 4; ++j)
        acc[i][j] = __builtin_amdgcn_mfma_f32_16x16x32_bf16(af[i], bfr[j], acc[i][j], 0, 0, 0);
    __builtin_amdgcn_s_setprio(0);
    __builtin_amdgcn_s_barrier();

    // ---- phase 4: kh1, M-frags 4..7 ----
    #pragma unroll
    for (int i = 0; i < 4; ++i) af[i] = *(const bf16x8*)&As[c][1][ri + (i+4)*16][kq8];
    STAGE_B(tn2, 0, c);
    __builtin_amdgcn_s_barrier();
    asm volatile("s_waitcnt lgkmcnt(0)" ::: "memory");
    __builtin_amdgcn_sched_barrier(0);
    __builtin_amdgcn_s_setprio(1);
    #pragma unroll
    for (int i = 0; i < 4; ++i)
      #pragma unroll
      for (int j = 0; j < 4; ++j)
        acc[i+4][j] = __builtin_amdgcn_mfma_f32_16x16x32_bf16(af[i], bfr[j], acc[i+4][j], 0, 0, 0);
    __builtin_amdgcn_s_setprio(0);
    asm volatile("s_waitcnt vmcnt(8)" ::: "memory");   // kh0 of tile t+1 landed
    __builtin_amdgcn_s_barrier();
  }
#undef STAGE_A
#undef STAGE_B

  // epilogue: C/D layout col=lane&15, row=(lane>>4)*4+reg
  const int cr = (lane >> 4) * 4;
  const int cc = lane & 15;
  #pragma unroll
  for (int i = 0; i < 8; ++i)
    #pragma unroll
    for (int j = 0; j < 4; ++j) {
      const int r_ = row0 + wr*128 + i*16 + cr;
      const int c_ = col0 + wc*64  + j*16 + cc;
      #pragma unroll
      for (int r = 0; r < 4; ++r) {
        const float v = acc[i][j][r];
        const size_t idx = (size_t)(r_ + r)*LDC + c_;
        if (OUT_MODE == 1)      ((uint16_t*)C)[idx] = f2bf(v);
        else if (OUT_MODE == 2) atomicAdd((float*)C + idx, v);
        else                    ((float*)C)[idx] = v;
      }
    }
}

// ---------------- segment helpers ----------------
// G layout per local row r (stride NW3): [0,HID)=w0, [HID,2HID)=z_pre, [2HID,3HID)=tilde_h

__device__ __forceinline__ void seg_info(const int* cuv, int ns, int t, int& ss, bool& st) {
  ss = 0; st = false;
  for (int i=0;i<ns;i++) { int cv = cuv[i]; if (cv<=t && cv>ss) ss=cv; if (cv==t) st=true; }
}

// ---------------- scan pass A: per-chunk conv+sigmoid+local scan ----------------
__global__ void scan_chunk(const uint16_t* __restrict__ G, int qstart,
                           const uint16_t* __restrict__ zprev,
                           const float* __restrict__ convw,
                           const int* __restrict__ cu, int ncu,
                           float* __restrict__ Ach, float* __restrict__ Bch)
{
  int h = blockIdx.x * blockDim.x + threadIdx.x;
  int c = blockIdx.y;
  if (h >= HID) return;
  const uint16_t* Z  = G + HID;
  const uint16_t* TH = G + 2*HID;
  float w0c = convw[h*4+0], w1c = convw[h*4+1], w2c = convw[h*4+2], w3c = convw[h*4+3];
  int cuv[8];
  int ns = ncu - 1; if (ns > 8) ns = 8;
  for (int i=0;i<ns;i++) cuv[i] = cu[i];
  int r0 = c * CHUNK;
  int t0 = qstart + r0;
  float z1, z2, z3;
  if (c == 0) {
    z1 = (t0-1 >= 0) ? bf2f(zprev[2*HID + h]) : 0.f;
    z2 = (t0-2 >= 0) ? bf2f(zprev[1*HID + h]) : 0.f;
    z3 = (t0-3 >= 0) ? bf2f(zprev[0*HID + h]) : 0.f;
  } else {
    z1 = bf2f(Z[(size_t)(r0-1)*NW3 + h]);
    z2 = bf2f(Z[(size_t)(r0-2)*NW3 + h]);
    z3 = bf2f(Z[(size_t)(r0-3)*NW3 + h]);
  }
  float Aacc = 1.f, Bacc = 0.f;
  for (int r = r0; r < r0 + CHUNK; ++r) {
    int t = qstart + r;
    float z0 = bf2f(Z[(size_t)r*NW3 + h]);
    float th = bf2f(TH[(size_t)r*NW3 + h]);
    int ss; bool st;
    seg_info(cuv, ns, t, ss, st);
    float s = z0*w3c;
    if (t-1 >= ss) s += z1*w2c;
    if (t-2 >= ss) s += z2*w1c;
    if (t-3 >= ss) s += z3*w0c;
    float zc = 1.f/(1.f + __expf(-s));
    float a = st ? 0.f : (1.f - zc);
    float b = zc * th;
    Aacc *= a;
    Bacc = a*Bacc + b;
    z3 = z2; z2 = z1; z1 = z0;
  }
  Ach[(size_t)c*HID + h] = Aacc;
  Bch[(size_t)c*HID + h] = Bacc;
}

// ---------------- scan pass B: combine chunk pairs; Hin written in place over Ach ----------------
__global__ void scan_combine(float* __restrict__ Ach, const float* __restrict__ Bch,
                             float* __restrict__ Sc, int first, int nchunk)
{
  int h = blockIdx.x * blockDim.x + threadIdx.x;
  if (h >= HID) return;
  float s = first ? 0.f : Sc[h];
  for (int c = 0; c < nchunk; ++c) {
    size_t idx = (size_t)c*HID + h;
    float a = Ach[idx], b = Bch[idx];
    Ach[idx] = s;                  // state entering chunk c (Hin)
    s = a*s + b;
  }
  Sc[h] = s;
}

// ---------------- scan pass C: fixup + h*silu(w0), hh written in place over TH ----------------
__global__ void scan_final(uint16_t* __restrict__ G, int qstart,
                           const uint16_t* __restrict__ zprev,
                           const float* __restrict__ convw,
                           const int* __restrict__ cu, int ncu,
                           const float* __restrict__ Hin)
{
  int h = blockIdx.x * blockDim.x + threadIdx.x;
  int c = blockIdx.y;
  if (h >= HID) return;
  const uint16_t* W0 = G;
  const uint16_t* Z  = G + HID;
  uint16_t*       TH = G + 2*HID;     // read th, then overwrite with hh
  float w0c = convw[h*4+0], w1c = convw[h*4+1], w2c = convw[h*4+2], w3c = convw[h*4+3];
  int cuv[8];
  int ns = ncu - 1; if (ns > 8) ns = 8;
  for (int i=0;i<ns;i++) cuv[i] = cu[i];
  int r0 = c * CHUNK;
  int t0 = qstart + r0;
  float z1, z2, z3;
  if (c == 0) {
    z1 = (t0-1 >= 0) ? bf2f(zprev[2*HID + h]) : 0.f;
    z2 = (t0-2 >= 0) ? bf2f(zprev[1*HID + h]) : 0.f;
    z3 = (t0-3 >= 0) ? bf2f(zprev[0*HID + h]) : 0.f;
  } else {
    z1 = bf2f(Z[(size_t)(r0-1)*NW3 + h]);
    z2 = bf2f(Z[(size_t)(r0-2)*NW3 + h]);
    z3 = bf2f(Z[(size_t)(r0-3)*NW3 + h]);
  }
  float state = Hin[(size_t)c*HID + h];
  for (int r = r0; r < r0 + CHUNK; ++r) {
    int t = qstart + r;
    float z0 = bf2f(Z[(size_t)r*NW3 + h]);
    float th = bf2f(TH[(size_t)r*NW3 + h]);
    int ss; bool st;
    seg_info(cuv, ns, t, ss, st);
    float s = z0*w3c;
    if (t-1 >= ss) s += z1*w2c;
    if (t-2 >= ss) s += z2*w1c;
    if (t-3 >= ss) s += z3*w0c;
    float zc = 1.f/(1.f + __expf(-s));
    float a = st ? 0.f : (1.f - zc);
    float b = zc * th;
    state = a*state + b;
    float w0v = bf2f(W0[(size_t)r*NW3 + h]);
    float silu = w0v / (1.f + __expf(-w0v));
    TH[(size_t)r*NW3 + h] = f2bf(state * silu);
    z3 = z2; z2 = z1; z1 = z0;
  }
}

// ---------------- save last 3 z-rows of this segment for next segment's conv taps ----------------
__global__ void save_ztail(const uint16_t* __restrict__ G, uint16_t* __restrict__ zprev, int qrows) {
  int i = blockIdx.x * blockDim.x + threadIdx.x;
  if (i >= 3*HID) return;
  int j = i / HID;        // 0,1,2 -> rows qrows-3+j
  int h = i - j*HID;
  zprev[i] = G[(size_t)(qrows-3+j)*NW3 + HID + h];
}

// ---------------- launcher ----------------
extern "C" void kernel_launch(void* const* d_in, const int* in_sizes, int n_in,
                              void* d_out, int out_size, void* d_ws, size_t ws_size,
                              hipStream_t stream) {
  const float* x     = (const float*)d_in[0];
  const int*   cu    = (const int*)d_in[1];
  const float* w_w   = (const float*)d_in[2];
  const float* wz_w  = (const float*)d_in[3];
  const float* wh_w  = (const float*)d_in[4];
  const float* wo_w  = (const float*)d_in[5];
  const float* convw = (const float*)d_in[6];
  const int ncu = in_sizes[1];
  float* out = (float*)d_out;

  // ---- tier selection: largest segment that fits ws ----
  const size_t base = 92331008ull;
  int qrows = 2048;
  if (ws_size >= base + 8192ull*38592ull) qrows = 8192;
  else if (ws_size >= base + 4096ull*38592ull) qrows = 4096;
  const int nq = SEQ / qrows;
  const int nchunk = qrows / CHUNK;

  // ---- workspace layout ----
  char* p = (char*)d_ws;
  uint16_t* w3b  = (uint16_t*)p; p += (size_t)NW3*DIM*2;       // 69.2 MB
  uint16_t* wob  = (uint16_t*)p; p += (size_t)DIM*HID*2;       // 23.1 MB
  float*    Sc   = (float*)p;    p += (size_t)HID*4;
  uint16_t* zprev= (uint16_t*)p; p += (size_t)3*HID*2;
  uint16_t* xseg = (uint16_t*)p; p += (size_t)qrows*DIM*2;
  uint16_t* G    = (uint16_t*)p; p += (size_t)qrows*NW3*2;
  float*    Ach  = (float*)p;    p += (size_t)nchunk*HID*4;    // doubles as Hin
  float*    Bch  = (float*)p;    p += (size_t)nchunk*HID*4;

  // ---- weight conversions (once) ----
  {
    int n4 = HID*DIM/4;
    cvt4_kernel<<<(n4+255)/256, 256, 0, stream>>>(w_w,  w3b, n4);
    cvt4_kernel<<<(n4+255)/256, 256, 0, stream>>>(wz_w, w3b + (size_t)HID*DIM, n4);
    cvt4_kernel<<<(n4+255)/256, 256, 0, stream>>>(wh_w, w3b + (size_t)2*HID*DIM, n4);
    n4 = DIM*HID/4;
    cvt4_kernel<<<(n4+255)/256, 256, 0, stream>>>(wo_w, wob, n4);
  }

  if (qrows < 8192)  // split-K atomics epilogue needs zeroed out
    hipMemsetAsync(out, 0, (size_t)out_size * sizeof(float), stream);

  for (int s = 0; s < nq; ++s) {
    const int qstart = s * qrows;

    // x segment -> bf16
    int n4 = qrows*DIM/4;
    cvt4_kernel<<<(n4+255)/256, 256, 0, stream>>>(x + (size_t)qstart*DIM, xseg, n4);

    // GEMM1: G = xseg @ [w_w;wz_w;wh_w]^T  (M=qrows, N=16896, K=2048)
    {
      const int nbx = qrows / 256;
      gemm256<DIM, DIM, NW3, DIM, 1><<<dim3(nbx * (NW3/256), 1), 512, 0, stream>>>(
          xseg, w3b, G, nbx);
    }

    // chunked scan with fused causal conv + gating
    scan_chunk  <<<dim3(HID/256, nchunk), 256, 0, stream>>>(G, qstart, zprev, convw, cu, ncu, Ach, Bch);
    scan_combine<<<HID/256, 256, 0, stream>>>(Ach, Bch, Sc, s == 0 ? 1 : 0, nchunk);
    scan_final  <<<dim3(HID/256, nchunk), 256, 0, stream>>>(G, qstart, zprev, convw, cu, ncu, Ach);

    if (s + 1 < nq)
      save_ztail<<<(3*HID+255)/256, 256, 0, stream>>>(G, zprev, qrows);

    // GEMM2: out[qstart:] = hh @ wo^T  (hh aliased over TH, lda=NW3; N=2048, K=5632)
    // split-K sized so total workgroups >= 256 (1 block/CU at 256^2 tiles)
    if (qrows == 8192) {
      gemm256<NW3, HID, DIM, HID, 0><<<dim3(32*(DIM/256), 1), 512, 0, stream>>>(
          G + 2*HID, wob, out + (size_t)qstart*DIM, 32);
    } else if (qrows == 4096) {
      gemm256<NW3, HID, DIM, HID/2, 2><<<dim3(16*(DIM/256), 2), 512, 0, stream>>>(
          G + 2*HID, wob, out + (size_t)qstart*DIM, 16);
    } else {
      gemm256<NW3, HID, DIM, HID/4, 2><<<dim3(8*(DIM/256), 4), 512, 0, stream>>>(
          G + 2*HID, wob, out + (size_t)qstart*DIM, 8);
    }
  }
}